// Round 1
// baseline (3301.749 us; speedup 1.0000x reference)
//
#include <hip/hip_runtime.h>
#include <math.h>

#define TOKENS 131072
#define HIDDEN 2048
#define NEXP 64
#define TOPK 8
#define TPW 16          // tokens per wave
#define WAVES 4         // waves per block
#define TPB (TPW*WAVES) // tokens per block = 64
#define KC 128          // k-chunk (floats) staged in LDS
#define KC4 (KC/4)      // 32 float4 per expert per chunk

// W chunk staged as lds_w[k4][expert] (float4), padded to 65 to break the
// 1 KiB write stride (32-way -> ~8-way on staging writes; reads stay
// conflict-free: lane stride = 16 B).
__global__ __launch_bounds__(256, 4) void gate_kernel(
    const float* __restrict__ x,
    const float* __restrict__ w,
    const float* __restrict__ bias,
    float* __restrict__ out_w,   // [TOKENS*TOPK] fp32
    float* __restrict__ out_i)   // [TOKENS*TOPK] expert indices stored as fp32
{
    __shared__ float4 lds_w[KC4][NEXP + 1];

    const int tid  = threadIdx.x;
    const int lane = tid & 63;                                   // = expert id
    const int wv   = __builtin_amdgcn_readfirstlane(tid >> 6);   // wave id (scalar)
    const int tok_base = blockIdx.x * TPB + wv * TPW;

    const float* xbase = x + (size_t)tok_base * HIDDEN;

    float acc[TPW];
#pragma unroll
    for (int t = 0; t < TPW; ++t) acc[t] = 0.f;

    for (int kc = 0; kc < HIDDEN / KC; ++kc) {
        const int kc_base = kc * KC;

        __syncthreads();
        // stage W[0:64][kc_base : kc_base+KC] -> LDS, coalesced global reads
#pragma unroll
        for (int r = 0; r < (NEXP * KC4) / 256; ++r) {
            int f  = r * 256 + tid;
            int e  = f >> 5;        // expert
            int k4 = f & 31;        // float4 index within chunk
            lds_w[k4][e] = *(const float4*)(w + (size_t)e * HIDDEN + kc_base + k4 * 4);
        }
        __syncthreads();

        for (int kk = 0; kk < KC4; ++kk) {
            const float4 wf = lds_w[kk][lane];
            const float* xk = xbase + kc_base + kk * 4;
#pragma unroll
            for (int t = 0; t < TPW; ++t) {
                const float4 xf = *(const float4*)(xk + t * HIDDEN);
                acc[t] = fmaf(xf.x, wf.x, acc[t]);
                acc[t] = fmaf(xf.y, wf.y, acc[t]);
                acc[t] = fmaf(xf.z, wf.z, acc[t]);
                acc[t] = fmaf(xf.w, wf.w, acc[t]);
            }
        }
    }

    const float bl = bias[lane];

#pragma unroll 1
    for (int t = 0; t < TPW; ++t) {
        const float v = acc[t];

        // softmax over the 64 lanes (= experts)
        float m = v;
#pragma unroll
        for (int off = 32; off > 0; off >>= 1)
            m = fmaxf(m, __shfl_xor(m, off));
        const float p = expf(v - m);
        float s = p;
#pragma unroll
        for (int off = 32; off > 0; off >>= 1)
            s += __shfl_xor(s, off);
        const float orig = p / s;          // un-biased softmax score

        float b = orig + bl;               // biased score used for selection

        float myw = 0.f, myi = 0.f;        // result slots for lanes 0..7
#pragma unroll 1
        for (int j = 0; j < TOPK; ++j) {
            // argmax over lanes, ties -> lowest expert index (stable top_k)
            float bv = b; int bi = lane;
#pragma unroll
            for (int off = 32; off > 0; off >>= 1) {
                const float ov = __shfl_xor(bv, off);
                const int   oi = __shfl_xor(bi, off);
                if (ov > bv || (ov == bv && oi < bi)) { bv = ov; bi = oi; }
            }
            const float wsel = __shfl(orig, bi);   // gather un-biased score
            if (lane == j)  { myw = wsel * 2.5f; myi = (float)bi; }
            if (lane == bi) b = -INFINITY;         // knock out the winner
        }

        const int tok = tok_base + t;
        if (lane < TOPK) {
            out_w[tok * TOPK + lane] = myw;
            out_i[tok * TOPK + lane] = myi;
        }
    }
}

extern "C" void kernel_launch(void* const* d_in, const int* in_sizes, int n_in,
                              void* d_out, int out_size, void* d_ws, size_t ws_size,
                              hipStream_t stream) {
    const float* x    = (const float*)d_in[0];
    const float* w    = (const float*)d_in[1];
    const float* bias = (const float*)d_in[2];
    float* out_w = (float*)d_out;
    float* out_i = (float*)d_out + (size_t)TOKENS * TOPK;

    dim3 grid(TOKENS / TPB), block(256);
    hipLaunchKernelGGL(gate_kernel, grid, block, 0, stream, x, w, bias, out_w, out_i);
}

// Round 2
// 2452.258 us; speedup vs baseline: 1.3464x; 1.3464x over previous
//
#include <hip/hip_runtime.h>
#include <math.h>

#define TOKENS 131072
#define HIDDEN 2048
#define NEXP 64
#define TOPK 8
#define KC 32                 // k-chunk staged per iteration
#define KC4 (KC/4)            // 8 float4 steps per chunk
#define RS (KC+4)             // LDS row stride in floats: 36 == 4 (mod 32) -> bank rotation, conflict-free frag reads
#define BTOK 128              // tokens per block (4 waves x 32)
#define WTOK 32               // tokens per wave
#define NCHUNK (HIDDEN/KC)    // 64

// Wave tile: 32 tokens x 64 experts. lane = el*8 + tl.
// Lane owns acc[i][j] = logit(token tl+8i, expert el+8j): 32 VGPR accumulators.
// Per 4-k step: 4 x-frag ds_read_b128 (8-way broadcast across el, banks disjoint
// across tl) + 8 w-frag ds_read_b128 (broadcast across tl, disjoint across el)
// feed 128 v_fma_f32 -> VALU-bound, no scalar-memory traffic in the loop.
__global__ __launch_bounds__(256, 4) void gate_kernel(
    const float* __restrict__ xg, const float* __restrict__ wg,
    const float* __restrict__ bias,
    float* __restrict__ out_w, float* __restrict__ out_i)
{
    __shared__ float xs[BTOK * RS];   // 18.0 KiB
    __shared__ float ws[NEXP * RS];   //  9.0 KiB

    const int tid  = threadIdx.x;
    const int lane = tid & 63;
    const int wv   = tid >> 6;      // wave 0..3
    const int tl   = lane & 7;      // token sub-lane
    const int el   = lane >> 3;     // expert sub-lane
    const int blk_tok = blockIdx.x * BTOK;

    // staging assignment: thread -> (row sr, float4-col sc); 8 threads cover a
    // 128 B row segment -> coalesced global loads
    const int sr = tid >> 3;        // 0..31
    const int sc = tid & 7;         // 0..7

    float acc[4][8];
#pragma unroll
    for (int i = 0; i < 4; ++i)
#pragma unroll
        for (int j = 0; j < 8; ++j) acc[i][j] = 0.f;

    float4 gx[4], gw[2];
    // prefetch chunk 0
#pragma unroll
    for (int p = 0; p < 4; ++p)
        gx[p] = *(const float4*)(xg + (size_t)(blk_tok + p*32 + sr) * HIDDEN + sc*4);
#pragma unroll
    for (int p = 0; p < 2; ++p)
        gw[p] = *(const float4*)(wg + (size_t)(p*32 + sr) * HIDDEN + sc*4);

    for (int kc = 0; kc < NCHUNK; ++kc) {
        if (kc) __syncthreads();          // previous chunk's readers done
#pragma unroll
        for (int p = 0; p < 4; ++p)
            *(float4*)&xs[(p*32 + sr)*RS + sc*4] = gx[p];
#pragma unroll
        for (int p = 0; p < 2; ++p)
            *(float4*)&ws[(p*32 + sr)*RS + sc*4] = gw[p];
        __syncthreads();                  // LDS chunk ready

        // prefetch next chunk; vmcnt-wait lands at next ds_write -> hidden by compute
        if (kc + 1 < NCHUNK) {
            const int kb = (kc + 1) * KC;
#pragma unroll
            for (int p = 0; p < 4; ++p)
                gx[p] = *(const float4*)(xg + (size_t)(blk_tok + p*32 + sr) * HIDDEN + kb + sc*4);
#pragma unroll
            for (int p = 0; p < 2; ++p)
                gw[p] = *(const float4*)(wg + (size_t)(p*32 + sr) * HIDDEN + kb + sc*4);
        }

#pragma unroll
        for (int kk = 0; kk < KC4; ++kk) {
            float4 xf[4], wf[8];
#pragma unroll
            for (int i = 0; i < 4; ++i)
                xf[i] = *(const float4*)&xs[(wv*WTOK + tl + 8*i)*RS + kk*4];
#pragma unroll
            for (int j = 0; j < 8; ++j)
                wf[j] = *(const float4*)&ws[(el + 8*j)*RS + kk*4];
#pragma unroll
            for (int i = 0; i < 4; ++i)
#pragma unroll
                for (int j = 0; j < 8; ++j) {
                    acc[i][j] = fmaf(xf[i].x, wf[j].x, acc[i][j]);
                    acc[i][j] = fmaf(xf[i].y, wf[j].y, acc[i][j]);
                    acc[i][j] = fmaf(xf[i].z, wf[j].z, acc[i][j]);
                    acc[i][j] = fmaf(xf[i].w, wf[j].w, acc[i][j]);
                }
        }
    }

    // per-lane bias values for its 8 experts (L1-cached, once)
    float bv8[8];
#pragma unroll
    for (int j = 0; j < 8; ++j) bv8[j] = bias[el + 8*j];

#pragma unroll 1
    for (int i = 0; i < 4; ++i) {
        const int tok = blk_tok + wv*WTOK + tl + 8*i;

        // softmax over 64 experts: 8 regs/lane x 8 lanes (same tl, el varies
        // over lane bits 3..5 -> butterfly with xor 8,16,32 stays in-group)
        float m = acc[i][0];
#pragma unroll
        for (int j = 1; j < 8; ++j) m = fmaxf(m, acc[i][j]);
#pragma unroll
        for (int d = 8; d < 64; d <<= 1) m = fmaxf(m, __shfl_xor(m, d));

        float pj[8], s = 0.f;
#pragma unroll
        for (int j = 0; j < 8; ++j) { pj[j] = expf(acc[i][j] - m); s += pj[j]; }
#pragma unroll
        for (int d = 8; d < 64; d <<= 1) s += __shfl_xor(s, d);

        float orig[8], bz[8];
#pragma unroll
        for (int j = 0; j < 8; ++j) { orig[j] = pj[j] / s; bz[j] = orig[j] + bv8[j]; }

        float rw = 0.f, ri = 0.f;
#pragma unroll 1
        for (int r = 0; r < TOPK; ++r) {
            // local argmax (strict > keeps lowest j -> lowest expert on ties)
            float bbv = bz[0]; int be = el; float bo = orig[0];
#pragma unroll
            for (int j = 1; j < 8; ++j)
                if (bz[j] > bbv) { bbv = bz[j]; be = el + 8*j; bo = orig[j]; }
            // cross-lane argmax, tie -> lowest expert index (stable top_k)
#pragma unroll
            for (int d = 8; d < 64; d <<= 1) {
                const float ov = __shfl_xor(bbv, d);
                const int   oe = __shfl_xor(be, d);
                const float oo = __shfl_xor(bo, d);
                if (ov > bbv || (ov == bbv && oe < be)) { bbv = ov; be = oe; bo = oo; }
            }
            if (el == r) { rw = bo * 2.5f; ri = (float)be; }
            // knock out winner
#pragma unroll
            for (int j = 0; j < 8; ++j)
                if (el + 8*j == be) bz[j] = -INFINITY;
        }
        out_w[(size_t)tok*TOPK + el] = rw;
        out_i[(size_t)tok*TOPK + el] = ri;
    }
}

extern "C" void kernel_launch(void* const* d_in, const int* in_sizes, int n_in,
                              void* d_out, int out_size, void* d_ws, size_t ws_size,
                              hipStream_t stream) {
    const float* x    = (const float*)d_in[0];
    const float* w    = (const float*)d_in[1];
    const float* bias = (const float*)d_in[2];
    float* out_w = (float*)d_out;
    float* out_i = (float*)d_out + (size_t)TOKENS * TOPK;

    dim3 grid(TOKENS / BTOK), block(256);
    hipLaunchKernelGGL(gate_kernel, grid, block, 0, stream, x, w, bias, out_w, out_i);
}